// Round 9
// baseline (320.198 us; speedup 1.0000x reference)
//
#include <hip/hip_runtime.h>
#include <hip/hip_bf16.h>

#define NB 256
#define NR 100
#define ND 6168
#define DP 6272            // 196 * 32
#define NH 128
#define NC 100
#define NW 196             // bit-words (=ktiles) per row
#define NWR 193            // words actually packed (ceil(6168/32))
#define ROWW 196           // word stride per row in bits array
#define BITS_B (NR * ROWW * 4)   // 78,400 B of bits per b
#define W1T_BYTES ((size_t)NH * DP * 2)
#define XBITS_BYTES ((size_t)NB * ROWW * 4)

// gemm LDS map
#define L_B   78848        // bits [100][196] u32 = 78,400; 448-B pad; then B ring
#define L_TOT (78848 + 4 * 8192)

typedef __attribute__((ext_vector_type(8))) __bf16 bf16x8;
typedef __attribute__((ext_vector_type(4))) float f32x4;
typedef __attribute__((ext_vector_type(4))) int i32x4;
typedef __attribute__((ext_vector_type(4))) unsigned int u32x4;
typedef unsigned int u32;

typedef const __attribute__((address_space(1))) u32* gas_ptr;
typedef __attribute__((address_space(3))) u32* las_ptr;

__device__ __forceinline__ void gload16(const void* g, void* l) {
  __builtin_amdgcn_global_load_lds((gas_ptr)g, (las_ptr)l, 16, 0, 0);
}

#define SB() __builtin_amdgcn_sched_barrier(0)
// Counted barrier: stage(t) landed when <=N vmem outstanding; all LDS reads
// done (lgkmcnt) so the next phase's DMA can overwrite ring slots safely.
#define VBAR(N) do { SB(); asm volatile("s_waitcnt vmcnt(" #N ")"); SB(); \
  asm volatile("s_waitcnt lgkmcnt(0)"); SB(); __builtin_amdgcn_s_barrier(); SB(); } while (0)

// ---------- prep 1: W1 (ND,NH) f32 -> W1T (NH, DP) bf16, zero-padded ----------
__global__ void prep_w1t(const float* __restrict__ W1, __hip_bfloat16* __restrict__ W1T) {
  __shared__ float tile[32][NH + 1];
  const int d0 = blockIdx.x * 32;
  const int t = threadIdx.x;
#pragma unroll
  for (int p = 0; p < 16; ++p) {
    int idx = p * 256 + t;
    int dd = idx >> 7;
    int h  = idx & 127;
    int d  = d0 + dd;
    tile[dd][h] = (d < ND) ? W1[d * NH + h] : 0.f;
  }
  __syncthreads();
#pragma unroll
  for (int p = 0; p < 16; ++p) {
    int idx = p * 256 + t;
    int h  = idx >> 5;
    int dd = idx & 31;
    W1T[h * DP + d0 + dd] = __float2bfloat16(tile[dd][h]);
  }
}

// ---------- prep 2: pack x -> xbits[b][196] ----------
__global__ void prep_xbits(const int* __restrict__ x, u32* __restrict__ xbits) {
  const int b = blockIdx.x, t = threadIdx.x;
  if (t >= NWR) return;
  const int* xp = x + (size_t)b * ND + t * 32;
  u32 wv = 0;
#pragma unroll
  for (int j = 0; j < 8; ++j) {
    if (t * 32 + j * 4 + 4 <= ND) {
      i32x4 v = *(const i32x4*)(xp + j * 4);
      wv |= ((u32)(v[0] & 1) << (4 * j))     | ((u32)(v[1] & 1) << (4 * j + 1))
          | ((u32)(v[2] & 1) << (4 * j + 2)) | ((u32)(v[3] & 1) << (4 * j + 3));
    }
  }
  xbits[(size_t)b * ROWW + t] = wv;
}

// ---------- kernel 1: pack (noise XOR x) -> bits, pure sequential streaming ----------
// grid (NR, NB): block = one (b, r) row slab (24.7 KB contiguous).
__global__ void pack_noise(const int* __restrict__ noise, const u32* __restrict__ xbits,
                           u32* __restrict__ bits) {
  const int r = blockIdx.x, b = blockIdx.y, t = threadIdx.x;
  if (t >= NWR) return;
  const int* np = noise + ((size_t)b * NR + r) * ND + t * 32;
  u32 wv = 0;
#pragma unroll
  for (int j = 0; j < 8; ++j) {
    if (t * 32 + j * 4 + 4 <= ND) {
      i32x4 v = *(const i32x4*)(np + j * 4);
      wv |= ((u32)(v[0] & 1) << (4 * j))     | ((u32)(v[1] & 1) << (4 * j + 1))
          | ((u32)(v[2] & 1) << (4 * j + 2)) | ((u32)(v[3] & 1) << (4 * j + 3));
    }
  }
  bits[((size_t)b * NR + r) * ROWW + t] = wv ^ xbits[(size_t)b * ROWW + t];
}

// ---------- kernel 2: LDS-resident bit-GEMM + fused epilogue ----------
// one block per b, 512 threads (8 waves = 4 wm x 2 wn). Wave-tile 32r x 64c.
__launch_bounds__(512, 1)
__global__ void gemm(const u32* __restrict__ bits, const __hip_bfloat16* __restrict__ W1T,
                     const float* __restrict__ b1, const float* __restrict__ W2,
                     const float* __restrict__ b2, float* __restrict__ out) {
  __shared__ __align__(16) char lds[L_TOT];
  const int tid  = threadIdx.x;
  const int lane = tid & 63;
  const int w    = tid >> 6;      // 0..7
  const int wm   = w >> 1;        // 0..3: rows wm*32..+32
  const int wn   = w & 1;         // 0..1: cols wn*64..+64
  const int lq   = lane >> 4;
  const int lm   = lane & 15;
  const int b    = blockIdx.x;

  // B-stage: one 8-KB W1T k-tile per phase, 1 DMA call per wave.
  const char* const bsrc0 = (const char*)W1T + (size_t)(16 * w + (lane >> 2)) * (DP * 2)
                            + (lane & 3) * 16;
  auto BSTAGE = [&](int t) {
    gload16(bsrc0 + t * 64, lds + L_B + (t & 3) * 8192 + w * 1024);
  };

  // ---- prologue: stage all bits for this b (linear) + B tiles 0..2 ----
  {
    const char* bb = (const char*)bits + (size_t)b * BITS_B;
    for (int c = w; c < 77; c += 8) {
      u32 off = (u32)(c * 1024 + lane * 16);
      if (off > BITS_B - 16) off = BITS_B - 16;   // tail clamp (dup reads -> pad)
      gload16(bb + off, lds + c * 1024);
    }
  }
  BSTAGE(0); BSTAGE(1); BSTAGE(2);
  __syncthreads();   // one-time full drain: bits + B(0..2) visible

  f32x4 acc[2][4] = {};
  const int rb0 = (wm * 32 + lm) * 784;         // bits byte base, mf=0
  const int rb1 = (wm * 32 + 16 + lm) * 784;    // mf=1
  const int lsh = lq * 8;

#pragma unroll 1
  for (int t = 0; t < NW; ++t) {
    VBAR(2);
    if (t + 3 < NW) BSTAGE(t + 3);
    const char* Bb = lds + L_B + (t & 3) * 8192;
    bf16x8 bf0 = *(const bf16x8*)(Bb + (wn * 64 + lm) * 64 + lq * 16);
    bf16x8 bf1 = *(const bf16x8*)(Bb + (wn * 64 + 16 + lm) * 64 + lq * 16);
    bf16x8 bf2 = *(const bf16x8*)(Bb + (wn * 64 + 32 + lm) * 64 + lq * 16);
    bf16x8 bf3 = *(const bf16x8*)(Bb + (wn * 64 + 48 + lm) * 64 + lq * 16);
#pragma unroll
    for (int mf = 0; mf < 2; ++mf) {
      u32 word = *(const u32*)(lds + (mf ? rb1 : rb0) + t * 4);
      u32 by = (word >> lsh) & 0xffu;
      u32 p0 = ((by & 1u)  ? 0x3F80u : 0u) | ((by & 2u)   ? 0x3F800000u : 0u);
      u32 p1 = ((by & 4u)  ? 0x3F80u : 0u) | ((by & 8u)   ? 0x3F800000u : 0u);
      u32 p2 = ((by & 16u) ? 0x3F80u : 0u) | ((by & 32u)  ? 0x3F800000u : 0u);
      u32 p3 = ((by & 64u) ? 0x3F80u : 0u) | ((by & 128u) ? 0x3F800000u : 0u);
      u32x4 pk = {p0, p1, p2, p3};
      bf16x8 af = *(bf16x8*)&pk;
      acc[mf][0] = __builtin_amdgcn_mfma_f32_16x16x32_bf16(af, bf0, acc[mf][0], 0, 0, 0);
      acc[mf][1] = __builtin_amdgcn_mfma_f32_16x16x32_bf16(af, bf1, acc[mf][1], 0, 0, 0);
      acc[mf][2] = __builtin_amdgcn_mfma_f32_16x16x32_bf16(af, bf2, acc[mf][2], 0, 0, 0);
      acc[mf][3] = __builtin_amdgcn_mfma_f32_16x16x32_bf16(af, bf3, acc[mf][3], 0, 0, 0);
    }
  }

  // ---- epilogue: mean over rows of tanh(acc + b1), fold through W2 ----
  __syncthreads();                       // all waves done reading bits region
  float* hpart = (float*)lds;            // [4][128] overlay
  float* hbar  = (float*)(lds + 2048);   // [128]
#pragma unroll
  for (int nf = 0; nf < 4; ++nf) {
    const int hcol = wn * 64 + nf * 16 + lm;
    const float bb = b1[hcol];
    float ssum = 0.f;
#pragma unroll
    for (int mf = 0; mf < 2; ++mf) {
#pragma unroll
      for (int rg = 0; rg < 4; ++rg) {
        int m = wm * 32 + mf * 16 + lq * 4 + rg;
        float tv = tanhf(acc[mf][nf][rg] + bb);
        ssum += (m < NR) ? tv : 0.f;
      }
    }
    ssum += __shfl_xor(ssum, 16, 64);
    ssum += __shfl_xor(ssum, 32, 64);
    if (lq == 0) hpart[wm * 128 + hcol] = ssum;
  }
  __syncthreads();
  if (tid < NH)
    hbar[tid] = (hpart[tid] + hpart[128 + tid] + hpart[256 + tid] + hpart[384 + tid]) * (1.0f / NR);
  __syncthreads();
  if (tid < NC) {
    float sacc = b2[tid];
#pragma unroll 8
    for (int h = 0; h < NH; ++h) sacc += hbar[h] * W2[h * NC + tid];
    out[b * NC + tid] = sacc;
  }
}

extern "C" void kernel_launch(void* const* d_in, const int* in_sizes, int n_in,
                              void* d_out, int out_size, void* d_ws, size_t ws_size,
                              hipStream_t stream) {
  (void)in_sizes; (void)n_in; (void)out_size; (void)ws_size;
  const int* x     = (const int*)d_in[0];
  const int* noise = (const int*)d_in[1];
  const float* W1  = (const float*)d_in[2];
  const float* b1  = (const float*)d_in[3];
  const float* W2  = (const float*)d_in[4];
  const float* b2  = (const float*)d_in[5];
  float* out = (float*)d_out;

  __hip_bfloat16* W1T = (__hip_bfloat16*)d_ws;
  u32* xbits = (u32*)((char*)d_ws + W1T_BYTES);
  u32* bits  = (u32*)((char*)d_ws + W1T_BYTES + XBITS_BYTES);

  prep_w1t<<<DP / 32, 256, 0, stream>>>(W1, W1T);
  prep_xbits<<<NB, 256, 0, stream>>>(x, xbits);
  pack_noise<<<dim3(NR, NB), 256, 0, stream>>>(noise, xbits, bits);
  gemm<<<NB, 512, 0, stream>>>(bits, W1T, b1, W2, b2, out);
}

// Round 11
// 249.138 us; speedup vs baseline: 1.2852x; 1.2852x over previous
//
#include <hip/hip_runtime.h>
#include <hip/hip_bf16.h>

#define NB 256
#define NR 100
#define ND 6168
#define DP 6272            // 196 * 32
#define NH 128
#define NC 100
#define NW 196             // bit-words (= ktiles) per row
#define ROWW 196
#define ROWB 784           // bytes of bits per row
#define BITS_B (NR * ROWB) // 78400 per b
#define CPR 25             // chunks (256 ints) per row
#define TOTAL_CHUNKS (NB * NR * CPR)  // 640000
#define W1T_BYTES ((size_t)NH * DP * 2)
#define XBITS_BYTES ((size_t)NB * ROWW * 4 + 1024)

// gemm LDS map
#define L_XB 0
#define L_BITS 1024
#define L_TOT (1024 + 77 * 1024)   // 79,872 B

typedef __attribute__((ext_vector_type(8))) __bf16 bf16x8;
typedef __attribute__((ext_vector_type(4))) float f32x4;
typedef __attribute__((ext_vector_type(4))) int i32x4;
typedef __attribute__((ext_vector_type(4))) unsigned int u32x4;
typedef unsigned int u32;
typedef unsigned long long u64;

typedef const __attribute__((address_space(1))) u32* gas_ptr;
typedef __attribute__((address_space(3))) u32* las_ptr;

__device__ __forceinline__ void gload16(const void* g, void* l) {
  __builtin_amdgcn_global_load_lds((gas_ptr)g, (las_ptr)l, 16, 0, 0);
}

// ---------- prep 1: W1 (ND,NH) f32 -> W1T (NH, DP) bf16, sigma-permuted ----------
// W1T[h][kbase + dd] = W1[kbase + sigma(dd)][h], sigma(dd) = (dd&7)*4 + (dd>>3):
// matches the ballot-packed bit order of A (slot pairing cancels element-exact).
__global__ void prep_w1t(const float* __restrict__ W1, __hip_bfloat16* __restrict__ W1T) {
  __shared__ float tile[32][NH + 1];
  const int d0 = blockIdx.x * 32;
  const int t = threadIdx.x;
#pragma unroll
  for (int p = 0; p < 16; ++p) {
    int idx = p * 256 + t;
    int dd = idx >> 7;
    int h  = idx & 127;
    int d  = d0 + dd;
    tile[dd][h] = (d < ND) ? W1[d * NH + h] : 0.f;
  }
  __syncthreads();
#pragma unroll
  for (int p = 0; p < 16; ++p) {
    int idx = p * 256 + t;
    int h  = idx >> 5;
    int dd = idx & 31;
    int sd = (dd & 7) * 4 + (dd >> 3);      // sigma
    W1T[h * DP + d0 + dd] = __float2bfloat16(tile[sd][h]);
  }
}

// ---------- ballot pack: one 256-int chunk -> 8 sigma-ordered words ----------
#define PACK_CHUNK(SRCBASE, K0, DSTROW, WJBASE)                                \
  do {                                                                         \
    int kc = ((K0) + 4 <= ND) ? (K0) : (ND - 4);                               \
    i32x4 v = *(const i32x4*)((SRCBASE) + kc);                                 \
    u64 M0 = __ballot((v[0] & 1) != 0);                                        \
    u64 M1 = __ballot((v[1] & 1) != 0);                                        \
    u64 M2 = __ballot((v[2] & 1) != 0);                                        \
    u64 M3 = __ballot((v[3] & 1) != 0);                                        \
    if (lane < 8) {                                                            \
      int wj = (WJBASE) + lane;                                                \
      if (wj < ROWW) {                                                         \
        int sh = 8 * lane;                                                     \
        u32 b0 = (u32)(M0 >> sh) & 0xffu;                                      \
        u32 b1 = (u32)(M1 >> sh) & 0xffu;                                      \
        u32 b2 = (u32)(M2 >> sh) & 0xffu;                                      \
        u32 b3 = (u32)(M3 >> sh) & 0xffu;                                      \
        (DSTROW)[wj] = b0 | (b1 << 8) | (b2 << 16) | (b3 << 24);               \
      }                                                                        \
    }                                                                          \
  } while (0)

// ---------- prep 2: pack x -> xbits[b][196] (sigma order) ----------
__global__ void prep_xbits(const int* __restrict__ x, u32* __restrict__ xbits) {
  const int b    = blockIdx.x;
  const int lane = threadIdx.x & 63;
  const int wv   = threadIdx.x >> 6;
  const int* src = x + (size_t)b * ND;
  u32* dst = xbits + (size_t)b * ROWW;
  for (int c = wv; c < CPR; c += 4)
    PACK_CHUNK(src, c * 256 + lane * 4, dst, c * 8);
}

// ---------- kernel 1: pack noise -> bits. Lane-contiguous streaming (m13 shape). ----------
__global__ void pack_noise(const int* __restrict__ noise, u32* __restrict__ bits) {
  const int lane = threadIdx.x & 63;
  const int wv   = threadIdx.x >> 6;
  for (int cw = blockIdx.x * 4 + wv; cw < TOTAL_CHUNKS; cw += 8192) {
    const int row = cw / CPR;               // b*NR + r
    const int c   = cw - row * CPR;
    const int* src = noise + (size_t)row * ND;
    u32* dst = bits + (size_t)row * ROWW;
    PACK_CHUNK(src, c * 256 + lane * 4, dst, c * 8);
  }
}

// ---------- kernel 2: barrier-free LDS-bit GEMM + fused epilogue ----------
// one block per b, 512 threads = 8 waves (2 wm x 4 wn); wave tile 64r x 32c.
__launch_bounds__(512, 1)
__global__ void gemm(const u32* __restrict__ bits, const __hip_bfloat16* __restrict__ W1T,
                     const float* __restrict__ b1, const u32* __restrict__ xbits,
                     const float* __restrict__ W2, const float* __restrict__ b2,
                     float* __restrict__ out) {
  __shared__ __align__(16) char lds[L_TOT];
  const int tid  = threadIdx.x;
  const int lane = tid & 63;
  const int w    = tid >> 6;      // 0..7
  const int wm   = w >> 2;        // 0..1: rows wm*64 .. +64
  const int wn   = w & 3;         // 0..3: cols wn*32 .. +32
  const int lq   = lane >> 4;
  const int lm   = lane & 15;
  const int b    = blockIdx.x;

  // ---- prologue: stage bits (77 KB) + xbits (784 B) to LDS, one drain ----
  {
    const char* bb = (const char*)bits + (size_t)b * BITS_B;
    for (int c = w; c < 77; c += 8) {
      u32 off = (u32)(c * 1024 + lane * 16);
      if (off > BITS_B - 16) off = BITS_B - 16;    // tail dup -> junk rows only
      gload16(bb + off, lds + L_BITS + c * 1024);
    }
    // per-lane SOURCE (guide m104): lane*16 on global; dest gets HW lane*16.
    // xbits alloc has +1024 slack, so the 1 KB read is in-bounds for all b.
    if (w == 0) gload16((const char*)(xbits + (size_t)b * ROWW) + lane * 16, lds + L_XB);
  }
  __syncthreads();   // the only barrier before the epilogue

  f32x4 acc[4][2] = {};
  int rcb[4];
#pragma unroll
  for (int mf = 0; mf < 4; ++mf) {
    int row = wm * 64 + mf * 16 + lm;
    rcb[mf] = ((row < NR) ? row : (NR - 1)) * ROWB;
  }
  const __hip_bfloat16* wsrcA = W1T + (size_t)(wn * 32 + lm) * DP + lq * 8;
  const __hip_bfloat16* wsrcB = W1T + (size_t)(wn * 32 + 16 + lm) * DP + lq * 8;
  const int lsh = lq * 8;

  auto BLOAD = [&](int t, bf16x8* Br) {
    Br[0] = *(const bf16x8*)(wsrcA + t * 32);
    Br[1] = *(const bf16x8*)(wsrcB + t * 32);
  };
  auto CONS = [&](int t, const bf16x8* Br) {
    u32 xw = *(const u32*)(lds + L_XB + t * 4);
#pragma unroll
    for (int mf = 0; mf < 4; ++mf) {
      u32 word = (*(const u32*)(lds + L_BITS + rcb[mf] + t * 4)) ^ xw;
      u32 by = (word >> lsh) & 0xffu;
      u32 p0 = ((by & 1u)  ? 0x3F80u : 0u) | ((by & 2u)   ? 0x3F800000u : 0u);
      u32 p1 = ((by & 4u)  ? 0x3F80u : 0u) | ((by & 8u)   ? 0x3F800000u : 0u);
      u32 p2 = ((by & 16u) ? 0x3F80u : 0u) | ((by & 32u)  ? 0x3F800000u : 0u);
      u32 p3 = ((by & 64u) ? 0x3F80u : 0u) | ((by & 128u) ? 0x3F800000u : 0u);
      u32x4 pk = {p0, p1, p2, p3};
      bf16x8 af = *(bf16x8*)&pk;
      acc[mf][0] = __builtin_amdgcn_mfma_f32_16x16x32_bf16(af, Br[0], acc[mf][0], 0, 0, 0);
      acc[mf][1] = __builtin_amdgcn_mfma_f32_16x16x32_bf16(af, Br[1], acc[mf][1], 0, 0, 0);
    }
  };

  bf16x8 Bc[2], Bn[2];
  BLOAD(0, Bc);
#pragma unroll 1
  for (int t = 0; t < NW; t += 2) {
    BLOAD(t + 1, Bn);
    CONS(t, Bc);
    BLOAD((t + 2 < NW) ? (t + 2) : (NW - 1), Bc);
    CONS(t + 1, Bn);
  }

  // ---- epilogue: mean over rows of tanh(acc + b1), fold through W2 ----
  __syncthreads();
  float* hpart = (float*)lds;            // [2][128] overlay
  float* hbar  = (float*)(lds + 1024);   // [128]
#pragma unroll
  for (int nf = 0; nf < 2; ++nf) {
    int hcol = wn * 32 + nf * 16 + lm;
    float bb = b1[hcol];
    float ssum = 0.f;
#pragma unroll
    for (int mf = 0; mf < 4; ++mf) {
#pragma unroll
      for (int rg = 0; rg < 4; ++rg) {
        int m = wm * 64 + mf * 16 + lq * 4 + rg;
        float tv = tanhf(acc[mf][nf][rg] + bb);
        ssum += (m < NR) ? tv : 0.f;
      }
    }
    ssum += __shfl_xor(ssum, 16, 64);
    ssum += __shfl_xor(ssum, 32, 64);
    if (lq == 0) hpart[wm * 128 + hcol] = ssum;
  }
  __syncthreads();
  if (tid < NH) hbar[tid] = (hpart[tid] + hpart[128 + tid]) * (1.0f / NR);
  __syncthreads();
  if (tid < NC) {
    float sacc = b2[tid];
#pragma unroll 8
    for (int h = 0; h < NH; ++h) sacc += hbar[h] * W2[h * NC + tid];
    out[b * NC + tid] = sacc;
  }
}

extern "C" void kernel_launch(void* const* d_in, const int* in_sizes, int n_in,
                              void* d_out, int out_size, void* d_ws, size_t ws_size,
                              hipStream_t stream) {
  (void)in_sizes; (void)n_in; (void)out_size; (void)ws_size;
  const int* x     = (const int*)d_in[0];
  const int* noise = (const int*)d_in[1];
  const float* W1  = (const float*)d_in[2];
  const float* b1  = (const float*)d_in[3];
  const float* W2  = (const float*)d_in[4];
  const float* b2  = (const float*)d_in[5];
  float* out = (float*)d_out;

  __hip_bfloat16* W1T = (__hip_bfloat16*)d_ws;
  u32* xbits = (u32*)((char*)d_ws + W1T_BYTES);
  u32* bits  = (u32*)((char*)d_ws + W1T_BYTES + XBITS_BYTES);

  prep_w1t<<<DP / 32, 256, 0, stream>>>(W1, W1T);
  prep_xbits<<<NB, 256, 0, stream>>>(x, xbits);
  pack_noise<<<2048, 256, 0, stream>>>(noise, bits);
  gemm<<<NB, 512, 0, stream>>>(bits, W1T, b1, xbits, W2, b2, out);
}

// Round 12
// 223.085 us; speedup vs baseline: 1.4353x; 1.1168x over previous
//
#include <hip/hip_runtime.h>
#include <hip/hip_bf16.h>

#define NB 256
#define NR 100
#define ND 6168
#define DP 6272            // 196 * 32
#define NH 128
#define NC 100
#define NW 196             // bit-words (= ktiles) per row
#define ROWW 196
#define ROWB 784           // bytes of bits per row
#define CPR 25             // 256-int chunks per row
#define NCHUNK (NR * CPR)  // 2500
#define W1T_BYTES ((size_t)NH * DP * 2)

// LDS map: [0,1024) xbits; [1024, 1024+78400) bits[100][196]
#define L_XB 0
#define L_BITS 1024
#define L_TOT (1024 + NR * ROWB)   // 79,424 B

typedef __attribute__((ext_vector_type(8))) __bf16 bf16x8;
typedef __attribute__((ext_vector_type(4))) float f32x4;
typedef __attribute__((ext_vector_type(4))) int i32x4;
typedef __attribute__((ext_vector_type(4))) unsigned int u32x4;
typedef unsigned int u32;
typedef unsigned long long u64;

// ---------- prep: W1 (ND,NH) f32 -> W1T (NH, DP) bf16, sigma-permuted ----------
// W1T[h][kbase+dd] = W1[kbase+sigma(dd)][h], sigma(dd) = (dd&7)*4 + (dd>>3):
// matches ballot bit order of A; zero where source d >= ND (covers tail junk).
__global__ void prep_w1t(const float* __restrict__ W1, __hip_bfloat16* __restrict__ W1T) {
  __shared__ float tile[32][NH + 1];
  const int d0 = blockIdx.x * 32;
  const int t = threadIdx.x;
#pragma unroll
  for (int p = 0; p < 16; ++p) {
    int idx = p * 256 + t;
    int dd = idx >> 7;
    int h  = idx & 127;
    int d  = d0 + dd;
    tile[dd][h] = (d < ND) ? W1[d * NH + h] : 0.f;
  }
  __syncthreads();
#pragma unroll
  for (int p = 0; p < 16; ++p) {
    int idx = p * 256 + t;
    int h  = idx >> 5;
    int dd = idx & 31;
    int sd = (dd & 7) * 4 + (dd >> 3);      // sigma
    W1T[h * DP + d0 + dd] = __float2bfloat16(tile[sd][h]);
  }
}

// ---------- fused: pack (ballot, in-LDS) + bit-GEMM + epilogue. 1 block/b ----------
__launch_bounds__(512, 1)
__global__ void fused(const int* __restrict__ x, const int* __restrict__ noise,
                      const __hip_bfloat16* __restrict__ W1T,
                      const float* __restrict__ b1, const float* __restrict__ W2,
                      const float* __restrict__ b2, float* __restrict__ out) {
  __shared__ __align__(16) char lds[L_TOT];
  u32* xb_lds   = (u32*)(lds + L_XB);
  u32* bits_lds = (u32*)(lds + L_BITS);

  const int tid  = threadIdx.x;
  const int lane = tid & 63;
  const int w    = tid >> 6;      // 0..7
  const int wm   = w >> 2;        // 0..1: rows wm*64 .. +64
  const int wn   = w & 3;         // 0..3: cols wn*32 .. +32
  const int lq   = lane >> 4;
  const int lm   = lane & 15;
  const int b    = blockIdx.x;

  // ================= phase A: ballot-pack x and noise into LDS =================
  {
    const int* xsrc = x + (size_t)b * ND;
#pragma unroll
    for (int j = 0; j < 4; ++j) {
      int c = w * 4 + j;
      if (c < CPR) {
        int k0 = c * 256 + lane * 4;
        int kc = (k0 + 4 <= ND) ? k0 : (ND - 4);
        i32x4 v = *(const i32x4*)(xsrc + kc);
        u64 M0 = __ballot((v[0] & 1) != 0);
        u64 M1 = __ballot((v[1] & 1) != 0);
        u64 M2 = __ballot((v[2] & 1) != 0);
        u64 M3 = __ballot((v[3] & 1) != 0);
        if (lane < 8) {
          int wj = c * 8 + lane;
          if (wj < ROWW) {
            int sh = 8 * lane;
            u32 c0 = (u32)(M0 >> sh) & 0xffu;
            u32 c1 = (u32)(M1 >> sh) & 0xffu;
            u32 c2 = (u32)(M2 >> sh) & 0xffu;
            u32 c3 = (u32)(M3 >> sh) & 0xffu;
            xb_lds[wj] = c0 | (c1 << 8) | (c2 << 16) | (c3 << 24);
          }
        }
      }
    }
  }
  {
    const int* nsrc = noise + (size_t)b * NR * ND;
#pragma unroll 1
    for (int i = 0; i < (NCHUNK + 31) / 32; ++i) {     // 79 iterations
      i32x4 v[4];
      int rr[4], cc[4];
#pragma unroll
      for (int j = 0; j < 4; ++j) {                    // 4 consecutive 1KB loads
        int q = i * 32 + w * 4 + j;
        q = (q < NCHUNK) ? q : (NCHUNK - 1);           // dup tail: same data, same dst
        int r = q / CPR;
        int c = q - r * CPR;
        rr[j] = r; cc[j] = c;
        int k0 = c * 256 + lane * 4;
        int kc = (k0 + 4 <= ND) ? k0 : (ND - 4);
        v[j] = *(const i32x4*)(nsrc + (size_t)r * ND + kc);
      }
#pragma unroll
      for (int j = 0; j < 4; ++j) {
        u64 M0 = __ballot((v[j][0] & 1) != 0);
        u64 M1 = __ballot((v[j][1] & 1) != 0);
        u64 M2 = __ballot((v[j][2] & 1) != 0);
        u64 M3 = __ballot((v[j][3] & 1) != 0);
        if (lane < 8) {
          int wj = cc[j] * 8 + lane;
          if (wj < ROWW) {
            int sh = 8 * lane;
            u32 c0 = (u32)(M0 >> sh) & 0xffu;
            u32 c1 = (u32)(M1 >> sh) & 0xffu;
            u32 c2 = (u32)(M2 >> sh) & 0xffu;
            u32 c3 = (u32)(M3 >> sh) & 0xffu;
            bits_lds[rr[j] * ROWW + wj] = c0 | (c1 << 8) | (c2 << 16) | (c3 << 24);
          }
        }
      }
    }
  }
  __syncthreads();   // bits + xbits visible to all waves

  // ================= phase B: barrier-free bit-GEMM (R11-validated) =================
  f32x4 acc[4][2] = {};
  int rcb[4];
#pragma unroll
  for (int mf = 0; mf < 4; ++mf) {
    int row = wm * 64 + mf * 16 + lm;
    rcb[mf] = ((row < NR) ? row : (NR - 1)) * ROWB;
  }
  const __hip_bfloat16* wsrcA = W1T + (size_t)(wn * 32 + lm) * DP + lq * 8;
  const __hip_bfloat16* wsrcB = W1T + (size_t)(wn * 32 + 16 + lm) * DP + lq * 8;
  const int lsh = lq * 8;

  auto BLOAD = [&](int t, bf16x8* Br) {
    Br[0] = *(const bf16x8*)(wsrcA + t * 32);
    Br[1] = *(const bf16x8*)(wsrcB + t * 32);
  };
  auto CONS = [&](int t, const bf16x8* Br) {
    u32 xw = *(const u32*)(lds + L_XB + t * 4);
#pragma unroll
    for (int mf = 0; mf < 4; ++mf) {
      u32 word = (*(const u32*)(lds + L_BITS + rcb[mf] + t * 4)) ^ xw;
      u32 by = (word >> lsh) & 0xffu;
      u32 p0 = ((by & 1u)  ? 0x3F80u : 0u) | ((by & 2u)   ? 0x3F800000u : 0u);
      u32 p1 = ((by & 4u)  ? 0x3F80u : 0u) | ((by & 8u)   ? 0x3F800000u : 0u);
      u32 p2 = ((by & 16u) ? 0x3F80u : 0u) | ((by & 32u)  ? 0x3F800000u : 0u);
      u32 p3 = ((by & 64u) ? 0x3F80u : 0u) | ((by & 128u) ? 0x3F800000u : 0u);
      u32x4 pk = {p0, p1, p2, p3};
      bf16x8 af = *(bf16x8*)&pk;
      acc[mf][0] = __builtin_amdgcn_mfma_f32_16x16x32_bf16(af, Br[0], acc[mf][0], 0, 0, 0);
      acc[mf][1] = __builtin_amdgcn_mfma_f32_16x16x32_bf16(af, Br[1], acc[mf][1], 0, 0, 0);
    }
  };

  bf16x8 Bc[2], Bn[2];
  BLOAD(0, Bc);
#pragma unroll 1
  for (int t = 0; t < NW; t += 2) {
    BLOAD(t + 1, Bn);
    CONS(t, Bc);
    BLOAD((t + 2 < NW) ? (t + 2) : (NW - 1), Bc);
    CONS(t + 1, Bn);
  }

  // ================= epilogue: tanh row-mean, fold through W2 =================
  __syncthreads();
  float* hpart = (float*)lds;            // [2][128] overlay (bits dead now)
  float* hbar  = (float*)(lds + 1024);   // [128]
#pragma unroll
  for (int nf = 0; nf < 2; ++nf) {
    int hcol = wn * 32 + nf * 16 + lm;
    float bb = b1[hcol];
    float ssum = 0.f;
#pragma unroll
    for (int mf = 0; mf < 4; ++mf) {
#pragma unroll
      for (int rg = 0; rg < 4; ++rg) {
        int m = wm * 64 + mf * 16 + lq * 4 + rg;
        float tv = tanhf(acc[mf][nf][rg] + bb);
        ssum += (m < NR) ? tv : 0.f;
      }
    }
    ssum += __shfl_xor(ssum, 16, 64);
    ssum += __shfl_xor(ssum, 32, 64);
    if (lq == 0) hpart[wm * 128 + hcol] = ssum;
  }
  __syncthreads();
  if (tid < NH) hbar[tid] = (hpart[tid] + hpart[128 + tid]) * (1.0f / NR);
  __syncthreads();
  if (tid < NC) {
    float sacc = b2[tid];
#pragma unroll 8
    for (int h = 0; h < NH; ++h) sacc += hbar[h] * W2[h * NC + tid];
    out[b * NC + tid] = sacc;
  }
}

extern "C" void kernel_launch(void* const* d_in, const int* in_sizes, int n_in,
                              void* d_out, int out_size, void* d_ws, size_t ws_size,
                              hipStream_t stream) {
  (void)in_sizes; (void)n_in; (void)out_size; (void)ws_size;
  const int* x     = (const int*)d_in[0];
  const int* noise = (const int*)d_in[1];
  const float* W1  = (const float*)d_in[2];
  const float* b1  = (const float*)d_in[3];
  const float* W2  = (const float*)d_in[4];
  const float* b2  = (const float*)d_in[5];
  float* out = (float*)d_out;

  __hip_bfloat16* W1T = (__hip_bfloat16*)d_ws;

  prep_w1t<<<DP / 32, 256, 0, stream>>>(W1, W1T);
  fused<<<NB, 512, 0, stream>>>(x, noise, W1T, b1, W2, b2, out);
}